// Round 1
// baseline (1291.151 us; speedup 1.0000x reference)
//
#include <hip/hip_runtime.h>
#include <cmath>

#define BB 8
#define HH 512
#define WW 512
#define HW (HH*WW)
#define RAD 15
#define SEG 64
#define EPS 0.001f
#define INV_K (1.0f/31.0f)

// ---------------- gray ----------------
__global__ __launch_bounds__(256) void k_gray(const float* __restrict__ I,
                                              float* __restrict__ g, int n) {
    int i = blockIdx.x * 256 + threadIdx.x;
    if (i >= n) return;
    int b = i / HW;
    int off = i - b * HW;
    const float* Ib = I + (size_t)b * 3 * HW;
    g[i] = 0.299f * Ib[off] + 0.587f * Ib[HW + off] + 0.114f * Ib[2 * HW + off];
}

// ---------------- horizontal box, 4 planes (g, p, g*p, g*g) ----------------
__global__ __launch_bounds__(256) void k_hbox4(const float* __restrict__ g,
                                               const float* __restrict__ p,
                                               float* __restrict__ hg, float* __restrict__ hp,
                                               float* __restrict__ hgp, float* __restrict__ hgg) {
    __shared__ float sg[WW], sp[WW];
    int bid = blockIdx.x;          // b*H + y
    int base = bid * WW;           // == b*HW + y*W
    int tid = threadIdx.x;
    for (int x = tid; x < WW; x += 256) { sg[x] = g[base + x]; sp[x] = p[base + x]; }
    __syncthreads();
    for (int x = tid; x < WW; x += 256) {
        float s0 = 0.f, s1 = 0.f, s2 = 0.f, s3 = 0.f;
        int lo = x - RAD < 0 ? 0 : x - RAD;
        int hi = x + RAD >= WW ? WW - 1 : x + RAD;
        for (int i = lo; i <= hi; ++i) {
            float gv = sg[i], pv = sp[i];
            s0 += gv; s1 += pv; s2 += gv * pv; s3 += gv * gv;
        }
        hg[base + x] = s0 * INV_K; hp[base + x] = s1 * INV_K;
        hgp[base + x] = s2 * INV_K; hgg[base + x] = s3 * INV_K;
    }
}

// ---------------- horizontal box, 2 planes (a, b) ----------------
__global__ __launch_bounds__(256) void k_hbox2(const float* __restrict__ pa,
                                               const float* __restrict__ pb,
                                               float* __restrict__ ha, float* __restrict__ hb) {
    __shared__ float sa[WW], sb[WW];
    int bid = blockIdx.x;
    int base = bid * WW;
    int tid = threadIdx.x;
    for (int x = tid; x < WW; x += 256) { sa[x] = pa[base + x]; sb[x] = pb[base + x]; }
    __syncthreads();
    for (int x = tid; x < WW; x += 256) {
        float s0 = 0.f, s1 = 0.f;
        int lo = x - RAD < 0 ? 0 : x - RAD;
        int hi = x + RAD >= WW ? WW - 1 : x + RAD;
        for (int i = lo; i <= hi; ++i) { s0 += sa[i]; s1 += sb[i]; }
        ha[base + x] = s0 * INV_K; hb[base + x] = s1 * INV_K;
    }
}

// ---------------- vertical box of 4 planes, fused a/b ----------------
__global__ __launch_bounds__(256) void k_vbox4_ab(const float* __restrict__ hg,
                                                  const float* __restrict__ hp,
                                                  const float* __restrict__ hgp,
                                                  const float* __restrict__ hgg,
                                                  float* __restrict__ a, float* __restrict__ bb) {
    int x = blockIdx.x * 256 + threadIdx.x;
    int b = blockIdx.y;
    int y0 = blockIdx.z * SEG;
    int pbase = b * HW + x;
    float s0 = 0.f, s1 = 0.f, s2 = 0.f, s3 = 0.f;
    int r0 = y0 - RAD < 0 ? 0 : y0 - RAD;
    for (int r = r0; r < y0 + RAD; ++r) {
        int o = pbase + r * WW;
        s0 += hg[o]; s1 += hp[o]; s2 += hgp[o]; s3 += hgg[o];
    }
    for (int y = y0; y < y0 + SEG; ++y) {
        if (y + RAD < HH) {
            int o = pbase + (y + RAD) * WW;
            s0 += hg[o]; s1 += hp[o]; s2 += hgp[o]; s3 += hgg[o];
        }
        float mI = s0 * INV_K, mP = s1 * INV_K, mIp = s2 * INV_K, mII = s3 * INV_K;
        float cov = mIp - mI * mP;
        float var = mII - mI * mI;
        float av = cov / (var + EPS);
        float bv = mP - av * mI;
        int o = pbase + y * WW;
        a[o] = av; bb[o] = bv;
        if (y - RAD >= 0) {
            int o2 = pbase + (y - RAD) * WW;
            s0 -= hg[o2]; s1 -= hp[o2]; s2 -= hgp[o2]; s3 -= hgg[o2];
        }
    }
}

// ---------------- vertical box of 2 planes, fused t_guided ----------------
__global__ __launch_bounds__(256) void k_vbox2_tg(const float* __restrict__ ha,
                                                  const float* __restrict__ hb,
                                                  const float* __restrict__ g,
                                                  float* __restrict__ tg) {
    int x = blockIdx.x * 256 + threadIdx.x;
    int b = blockIdx.y;
    int y0 = blockIdx.z * SEG;
    int pbase = b * HW + x;
    float s0 = 0.f, s1 = 0.f;
    int r0 = y0 - RAD < 0 ? 0 : y0 - RAD;
    for (int r = r0; r < y0 + RAD; ++r) {
        int o = pbase + r * WW;
        s0 += ha[o]; s1 += hb[o];
    }
    for (int y = y0; y < y0 + SEG; ++y) {
        if (y + RAD < HH) {
            int o = pbase + (y + RAD) * WW;
            s0 += ha[o]; s1 += hb[o];
        }
        int o = pbase + y * WW;
        tg[o] = (s0 * INV_K) * g[o] + (s1 * INV_K);
        if (y - RAD >= 0) {
            int o2 = pbase + (y - RAD) * WW;
            s0 -= ha[o2]; s1 -= hb[o2];
        }
    }
}

// ---------------- conv1: feats(8ch: I0..2, tg, dark, A0..2) -> 32, relu ----------------
__global__ __launch_bounds__(256) void k_conv1(const float* __restrict__ I,
                                               const float* __restrict__ tg,
                                               const float* __restrict__ dark,
                                               const float* __restrict__ A,
                                               const float* __restrict__ W1,
                                               const float* __restrict__ b1,
                                               float* __restrict__ out, int batch) {
    int x = blockIdx.x * 256 + threadIdx.x;
    int y = blockIdx.y;
    int co0 = blockIdx.z * 8;
    float acc[8];
#pragma unroll
    for (int o = 0; o < 8; ++o) acc[o] = b1[co0 + o];
    const float* Ib = I + (size_t)batch * 3 * HW;
    const float* tgb = tg + (size_t)batch * HW;
    const float* db = dark + (size_t)batch * HW;
    float Ab0 = A[batch * 3 + 0], Ab1 = A[batch * 3 + 1], Ab2 = A[batch * 3 + 2];
#pragma unroll
    for (int ci = 0; ci < 8; ++ci) {
#pragma unroll
        for (int dy = -1; dy <= 1; ++dy) {
            int yy = y + dy;
            bool yok = (yy >= 0) && (yy < HH);
#pragma unroll
            for (int dx = -1; dx <= 1; ++dx) {
                int xx = x + dx;
                bool ok = yok && (xx >= 0) && (xx < WW);
                float v = 0.f;
                if (ok) {
                    int off = yy * WW + xx;
                    v = (ci < 3) ? Ib[ci * HW + off]
                      : (ci == 3) ? tgb[off]
                      : (ci == 4) ? db[off]
                      : (ci == 5) ? Ab0 : (ci == 6) ? Ab1 : Ab2;
                }
                int widx = ci * 9 + (dy + 1) * 3 + (dx + 1);
#pragma unroll
                for (int o = 0; o < 8; ++o) acc[o] += v * W1[(co0 + o) * 72 + widx];
            }
        }
    }
    int off = y * WW + x;
#pragma unroll
    for (int o = 0; o < 8; ++o) out[(co0 + o) * HW + off] = fmaxf(acc[o], 0.f);
}

// ---------------- conv2: 32 -> 16, relu ----------------
__global__ __launch_bounds__(256) void k_conv2(const float* __restrict__ in,
                                               const float* __restrict__ W2,
                                               const float* __restrict__ b2,
                                               float* __restrict__ out) {
    int x = blockIdx.x * 256 + threadIdx.x;
    int y = blockIdx.y;
    int co0 = blockIdx.z * 8;
    float acc[8];
#pragma unroll
    for (int o = 0; o < 8; ++o) acc[o] = b2[co0 + o];
    for (int ci = 0; ci < 32; ++ci) {
        const float* inc = in + ci * HW;
#pragma unroll
        for (int dy = -1; dy <= 1; ++dy) {
            int yy = y + dy;
            bool yok = (yy >= 0) && (yy < HH);
#pragma unroll
            for (int dx = -1; dx <= 1; ++dx) {
                int xx = x + dx;
                float v = (yok && xx >= 0 && xx < WW) ? inc[yy * WW + xx] : 0.f;
                int widx = ci * 9 + (dy + 1) * 3 + (dx + 1);
#pragma unroll
                for (int o = 0; o < 8; ++o) acc[o] += v * W2[(co0 + o) * 288 + widx];
            }
        }
    }
    int off = y * WW + x;
#pragma unroll
    for (int o = 0; o < 8; ++o) out[(co0 + o) * HW + off] = fmaxf(acc[o], 0.f);
}

// ---------------- conv3: 16 -> 1, sigmoid, blend, clip ----------------
__global__ __launch_bounds__(256) void k_conv3_final(const float* __restrict__ in,
                                                     const float* __restrict__ W3,
                                                     const float* __restrict__ b3,
                                                     const float* __restrict__ tgb,
                                                     float* __restrict__ outb) {
    int x = blockIdx.x * 256 + threadIdx.x;
    int y = blockIdx.y;
    float acc = b3[0];
    for (int ci = 0; ci < 16; ++ci) {
        const float* inc = in + ci * HW;
#pragma unroll
        for (int dy = -1; dy <= 1; ++dy) {
            int yy = y + dy;
            bool yok = (yy >= 0) && (yy < HH);
#pragma unroll
            for (int dx = -1; dx <= 1; ++dx) {
                int xx = x + dx;
                float v = (yok && xx >= 0 && xx < WW) ? inc[yy * WW + xx] : 0.f;
                acc += v * W3[ci * 9 + (dy + 1) * 3 + (dx + 1)];
            }
        }
    }
    float sg = 1.f / (1.f + expf(-acc));
    int off = y * WW + x;
    float tf = 0.7f * tgb[off] + 0.3f * sg;
    outb[off] = fminf(fmaxf(tf, 0.f), 1.f);
}

extern "C" void kernel_launch(void* const* d_in, const int* in_sizes, int n_in,
                              void* d_out, int out_size, void* d_ws, size_t ws_size,
                              hipStream_t stream) {
    const float* I    = (const float*)d_in[0];
    const float* t0   = (const float*)d_in[1];
    const float* dark = (const float*)d_in[2];
    const float* A    = (const float*)d_in[3];
    const float* W1   = (const float*)d_in[4];
    const float* b1   = (const float*)d_in[5];
    const float* W2   = (const float*)d_in[6];
    const float* b2   = (const float*)d_in[7];
    const float* W3   = (const float*)d_in[8];
    const float* b3   = (const float*)d_in[9];
    float* out = (float*)d_out;
    float* ws  = (float*)d_ws;

    const size_t P = (size_t)BB * HW;   // 2,097,152 floats = 8 MiB
    float* g   = ws;            // [0,P)
    float* hg  = ws + 1 * P;    // [P,5P): hbox outputs
    float* hp  = ws + 2 * P;
    float* hgp = ws + 3 * P;
    float* hgg = ws + 4 * P;
    float* a   = ws + 5 * P;    // [5P,7P)
    float* bb  = ws + 6 * P;
    float* ha  = ws + 7 * P;    // [7P,9P)
    float* hb  = ws + 8 * P;
    float* tg  = ws + 5 * P;    // reuse a's slot (a consumed by hbox2 before vbox2 writes tg)
    float* h1  = ws;            // per-batch conv1 out, 32ch = 4P (g/hg/hp/hgp dead by then)
    float* h2  = ws + 6 * P;    // per-batch conv2 out, 16ch = 2P (bb/ha dead by then)

    k_gray<<<(int)((P + 255) / 256), 256, 0, stream>>>(I, g, (int)P);
    k_hbox4<<<BB * HH, 256, 0, stream>>>(g, t0, hg, hp, hgp, hgg);
    dim3 gv(WW / 256, BB, HH / SEG);
    k_vbox4_ab<<<gv, 256, 0, stream>>>(hg, hp, hgp, hgg, a, bb);
    k_hbox2<<<BB * HH, 256, 0, stream>>>(a, bb, ha, hb);
    k_vbox2_tg<<<gv, 256, 0, stream>>>(ha, hb, g, tg);

    for (int b = 0; b < BB; ++b) {
        dim3 g1(WW / 256, HH, 4);
        k_conv1<<<g1, 256, 0, stream>>>(I, tg, dark, A, W1, b1, h1, b);
        dim3 g2(WW / 256, HH, 2);
        k_conv2<<<g2, 256, 0, stream>>>(h1, W2, b2, h2);
        dim3 g3(WW / 256, HH, 1);
        k_conv3_final<<<g3, 256, 0, stream>>>(h2, W3, b3, tg + (size_t)b * HW,
                                              out + (size_t)b * HW);
    }
}

// Round 2
// 582.882 us; speedup vs baseline: 2.2151x; 2.2151x over previous
//
#include <hip/hip_runtime.h>
#include <cmath>

#define BB 8
#define HH 512
#define WW 512
#define HW (HH*WW)
#define RAD 15
#define SEG 16
#define EPS 0.001f
#define INV_K (1.0f/31.0f)

typedef short bf16x8 __attribute__((ext_vector_type(8)));
typedef short bf16x4 __attribute__((ext_vector_type(4)));
typedef float f32x4 __attribute__((ext_vector_type(4)));

static __device__ inline short f2bf(float f) {
    unsigned int u = __float_as_uint(f);
    unsigned int r = (u + 0x7FFFu + ((u >> 16) & 1u)) >> 16;   // RNE
    return (short)r;
}
static __device__ inline float bf2f(short s) {
    return __uint_as_float(((unsigned int)(unsigned short)s) << 16);
}

// ---------------- gray ----------------
__global__ __launch_bounds__(256) void k_gray(const float* __restrict__ I,
                                              float* __restrict__ g, int n) {
    int i = blockIdx.x * 256 + threadIdx.x;
    if (i >= n) return;
    int b = i >> 18;
    int off = i & (HW - 1);
    const float* Ib = I + (size_t)b * 3 * HW;
    g[i] = 0.299f * Ib[off] + 0.587f * Ib[HW + off] + 0.114f * Ib[2 * HW + off];
}

// ---------------- horizontal box, 4 planes (g, p, g*p, g*g) ----------------
__global__ __launch_bounds__(256) void k_hbox4(const float* __restrict__ g,
                                               const float* __restrict__ p,
                                               float* __restrict__ hg, float* __restrict__ hp,
                                               float* __restrict__ hgp, float* __restrict__ hgg) {
    __shared__ float sg[WW], sp[WW];
    int base = blockIdx.x * WW;
    int tid = threadIdx.x;
    for (int x = tid; x < WW; x += 256) { sg[x] = g[base + x]; sp[x] = p[base + x]; }
    __syncthreads();
    for (int x = tid; x < WW; x += 256) {
        float s0 = 0.f, s1 = 0.f, s2 = 0.f, s3 = 0.f;
        int lo = x - RAD < 0 ? 0 : x - RAD;
        int hi = x + RAD >= WW ? WW - 1 : x + RAD;
        for (int i = lo; i <= hi; ++i) {
            float gv = sg[i], pv = sp[i];
            s0 += gv; s1 += pv; s2 += gv * pv; s3 += gv * gv;
        }
        hg[base + x] = s0 * INV_K; hp[base + x] = s1 * INV_K;
        hgp[base + x] = s2 * INV_K; hgg[base + x] = s3 * INV_K;
    }
}

// ---------------- horizontal box, 2 planes (a, b) ----------------
__global__ __launch_bounds__(256) void k_hbox2(const float* __restrict__ pa,
                                               const float* __restrict__ pb,
                                               float* __restrict__ ha, float* __restrict__ hb) {
    __shared__ float sa[WW], sb[WW];
    int base = blockIdx.x * WW;
    int tid = threadIdx.x;
    for (int x = tid; x < WW; x += 256) { sa[x] = pa[base + x]; sb[x] = pb[base + x]; }
    __syncthreads();
    for (int x = tid; x < WW; x += 256) {
        float s0 = 0.f, s1 = 0.f;
        int lo = x - RAD < 0 ? 0 : x - RAD;
        int hi = x + RAD >= WW ? WW - 1 : x + RAD;
        for (int i = lo; i <= hi; ++i) { s0 += sa[i]; s1 += sb[i]; }
        ha[base + x] = s0 * INV_K; hb[base + x] = s1 * INV_K;
    }
}

// ---------------- vertical box of 4 planes, fused a/b ----------------
__global__ __launch_bounds__(256) void k_vbox4_ab(const float* __restrict__ hg,
                                                  const float* __restrict__ hp,
                                                  const float* __restrict__ hgp,
                                                  const float* __restrict__ hgg,
                                                  float* __restrict__ a, float* __restrict__ bb) {
    int x = blockIdx.x * 256 + threadIdx.x;
    int b = blockIdx.y;
    int y0 = blockIdx.z * SEG;
    int pbase = b * HW + x;
    float s0 = 0.f, s1 = 0.f, s2 = 0.f, s3 = 0.f;
    int r0 = y0 - RAD < 0 ? 0 : y0 - RAD;
    for (int r = r0; r < y0 + RAD; ++r) {
        int o = pbase + r * WW;
        s0 += hg[o]; s1 += hp[o]; s2 += hgp[o]; s3 += hgg[o];
    }
    for (int y = y0; y < y0 + SEG; ++y) {
        if (y + RAD < HH) {
            int o = pbase + (y + RAD) * WW;
            s0 += hg[o]; s1 += hp[o]; s2 += hgp[o]; s3 += hgg[o];
        }
        float mI = s0 * INV_K, mP = s1 * INV_K, mIp = s2 * INV_K, mII = s3 * INV_K;
        float cov = mIp - mI * mP;
        float var = mII - mI * mI;
        float av = cov / (var + EPS);
        float bv = mP - av * mI;
        int o = pbase + y * WW;
        a[o] = av; bb[o] = bv;
        if (y - RAD >= 0) {
            int o2 = pbase + (y - RAD) * WW;
            s0 -= hg[o2]; s1 -= hp[o2]; s2 -= hgp[o2]; s3 -= hgg[o2];
        }
    }
}

// ---------------- vertical box of 2 planes, fused t_guided ----------------
__global__ __launch_bounds__(256) void k_vbox2_tg(const float* __restrict__ ha,
                                                  const float* __restrict__ hb,
                                                  const float* __restrict__ g,
                                                  float* __restrict__ tg) {
    int x = blockIdx.x * 256 + threadIdx.x;
    int b = blockIdx.y;
    int y0 = blockIdx.z * SEG;
    int pbase = b * HW + x;
    float s0 = 0.f, s1 = 0.f;
    int r0 = y0 - RAD < 0 ? 0 : y0 - RAD;
    for (int r = r0; r < y0 + RAD; ++r) {
        int o = pbase + r * WW;
        s0 += ha[o]; s1 += hb[o];
    }
    for (int y = y0; y < y0 + SEG; ++y) {
        if (y + RAD < HH) {
            int o = pbase + (y + RAD) * WW;
            s0 += ha[o]; s1 += hb[o];
        }
        int o = pbase + y * WW;
        tg[o] = (s0 * INV_K) * g[o] + (s1 * INV_K);
        if (y - RAD >= 0) {
            int o2 = pbase + (y - RAD) * WW;
            s0 -= ha[o2]; s1 -= hb[o2];
        }
    }
}

// ---------------- feats: NHWC bf16 [B][H][W][8] = {I0,I1,I2,tg,dark,A0,A1,A2} ----------------
__global__ __launch_bounds__(256) void k_feats(const float* __restrict__ I,
                                               const float* __restrict__ tg,
                                               const float* __restrict__ dark,
                                               const float* __restrict__ A,
                                               short* __restrict__ feats) {
    int i = blockIdx.x * 256 + threadIdx.x;   // over B*HW
    int b = i >> 18;
    int off = i & (HW - 1);
    const float* Ib = I + (size_t)b * 3 * HW;
    bf16x8 v;
    v[0] = f2bf(Ib[off]);
    v[1] = f2bf(Ib[HW + off]);
    v[2] = f2bf(Ib[2 * HW + off]);
    v[3] = f2bf(tg[i]);
    v[4] = f2bf(dark[i]);
    v[5] = f2bf(A[b * 3 + 0]);
    v[6] = f2bf(A[b * 3 + 1]);
    v[7] = f2bf(A[b * 3 + 2]);
    *(bf16x8*)(feats + (size_t)i * 8) = v;
}

// ---------------- conv1 MFMA: feats[.][8] -> h1[.][32], relu ----------------
// K packed as k = s*8 + ci, s=(dy+1)*3+(dx+1) in 0..8, padded to 96 (3 MFMA K-steps)
__global__ __launch_bounds__(256) void k_conv1_mfma(const short* __restrict__ feats,
                                                    const float* __restrict__ W1,
                                                    const float* __restrict__ b1,
                                                    short* __restrict__ h1) {
    int tid = threadIdx.x;
    int lane = tid & 63;
    int wave = tid >> 6;
    int y  = blockIdx.x >> 1;
    int x0 = (blockIdx.x & 1) * 256 + wave * 64;
    int j = lane & 15;      // pixel-in-frag / co-in-group
    int g = lane >> 4;      // k-group

    // A frags: wA[cg][t], lane holds W1[co= cg*16+j][k = t*32 + g*8 + i]
    bf16x8 wA[2][3];
#pragma unroll
    for (int cg = 0; cg < 2; ++cg) {
        int co = cg * 16 + j;
#pragma unroll
        for (int t = 0; t < 3; ++t) {
            int s = t * 4 + g;
            bf16x8 w;
#pragma unroll
            for (int i = 0; i < 8; ++i)
                w[i] = (s < 9) ? f2bf(W1[co * 72 + i * 9 + s]) : (short)0;
            wA[cg][t] = w;
        }
    }

    f32x4 acc[2][4] = {};
    const bf16x8 zerov = {0,0,0,0,0,0,0,0};
#pragma unroll
    for (int t = 0; t < 3; ++t) {
        int s = t * 4 + g;
        int dy = s / 3 - 1, dx = s % 3 - 1;
        int yy = y + dy;
        bf16x8 Bv[4];
#pragma unroll
        for (int n = 0; n < 4; ++n) {
            int xx = x0 + n * 16 + j + dx;
            bool ok = (s < 9) && yy >= 0 && yy < HH && xx >= 0 && xx < WW;
            int yc = yy < 0 ? 0 : (yy > HH - 1 ? HH - 1 : yy);
            int xc = xx < 0 ? 0 : (xx > WW - 1 ? WW - 1 : xx);
            bf16x8 v = *(const bf16x8*)(feats + ((size_t)yc * WW + xc) * 8);
            Bv[n] = ok ? v : zerov;
        }
#pragma unroll
        for (int cg = 0; cg < 2; ++cg)
#pragma unroll
            for (int n = 0; n < 4; ++n)
                acc[cg][n] = __builtin_amdgcn_mfma_f32_16x16x32_bf16(wA[cg][t], Bv[n], acc[cg][n], 0, 0, 0);
    }

    // epilogue: D col=lane&15 (pixel), row=g*4+r (co-in-group)
#pragma unroll
    for (int cg = 0; cg < 2; ++cg) {
        int co0 = cg * 16 + g * 4;
        float bias[4];
#pragma unroll
        for (int r = 0; r < 4; ++r) bias[r] = b1[co0 + r];
#pragma unroll
        for (int n = 0; n < 4; ++n) {
            int pix = y * WW + x0 + n * 16 + j;
            bf16x4 o;
#pragma unroll
            for (int r = 0; r < 4; ++r) o[r] = f2bf(fmaxf(acc[cg][n][r] + bias[r], 0.f));
            *(bf16x4*)(h1 + (size_t)pix * 32 + co0) = o;
        }
    }
}

// ---------------- conv2 MFMA: h1[.][32] -> h2[.][16], relu ----------------
__global__ __launch_bounds__(256) void k_conv2_mfma(const short* __restrict__ h1,
                                                    const float* __restrict__ W2,
                                                    const float* __restrict__ b2,
                                                    short* __restrict__ h2) {
    int tid = threadIdx.x;
    int lane = tid & 63;
    int wave = tid >> 6;
    int y  = blockIdx.x >> 1;
    int x0 = (blockIdx.x & 1) * 256 + wave * 64;
    int j = lane & 15;
    int g = lane >> 4;
    int ci0 = g * 8;

    bf16x8 wA[9];
#pragma unroll
    for (int s = 0; s < 9; ++s) {
        bf16x8 w;
#pragma unroll
        for (int i = 0; i < 8; ++i)
            w[i] = f2bf(W2[j * 288 + (ci0 + i) * 9 + s]);
        wA[s] = w;
    }

    f32x4 acc[4] = {};
    const bf16x8 zerov = {0,0,0,0,0,0,0,0};
#pragma unroll
    for (int dy = -1; dy <= 1; ++dy) {
        int yy = y + dy;
        if (yy >= 0 && yy < HH) {
            const short* rowp = h1 + (size_t)yy * WW * 32;
#pragma unroll
            for (int dx = -1; dx <= 1; ++dx) {
                int s = (dy + 1) * 3 + (dx + 1);
#pragma unroll
                for (int n = 0; n < 4; ++n) {
                    int xx = x0 + n * 16 + j + dx;
                    bool ok = (xx >= 0) && (xx < WW);
                    int xc = ok ? xx : 0;
                    bf16x8 v = *(const bf16x8*)(rowp + (size_t)xc * 32 + ci0);
                    acc[n] = __builtin_amdgcn_mfma_f32_16x16x32_bf16(wA[s], ok ? v : zerov, acc[n], 0, 0, 0);
                }
            }
        }
    }

    int co0 = g * 4;
    float bias[4];
#pragma unroll
    for (int r = 0; r < 4; ++r) bias[r] = b2[co0 + r];
#pragma unroll
    for (int n = 0; n < 4; ++n) {
        int pix = y * WW + x0 + n * 16 + j;
        bf16x4 o;
#pragma unroll
        for (int r = 0; r < 4; ++r) o[r] = f2bf(fmaxf(acc[n][r] + bias[r], 0.f));
        *(bf16x4*)(h2 + (size_t)pix * 16 + co0) = o;
    }
}

// ---------------- conv3: h2[.][16] -> 1, sigmoid, blend, clip ----------------
__global__ __launch_bounds__(256) void k_conv3_final(const short* __restrict__ h2,
                                                     const float* __restrict__ W3,
                                                     const float* __restrict__ b3,
                                                     const float* __restrict__ tgb,
                                                     float* __restrict__ outb) {
    int i = blockIdx.x * 256 + threadIdx.x;   // pixel in batch
    int y = i >> 9;
    int x = i & (WW - 1);
    float acc = b3[0];
#pragma unroll
    for (int dy = -1; dy <= 1; ++dy) {
        int yy = y + dy;
        bool yok = (yy >= 0) && (yy < HH);
#pragma unroll
        for (int dx = -1; dx <= 1; ++dx) {
            int xx = x + dx;
            bool ok = yok && xx >= 0 && xx < WW;
            int yc = yy < 0 ? 0 : (yy > HH - 1 ? HH - 1 : yy);
            int xc = xx < 0 ? 0 : (xx > WW - 1 ? WW - 1 : xx);
            const short* p = h2 + ((size_t)yc * WW + xc) * 16;
            bf16x8 v0 = *(const bf16x8*)(p);
            bf16x8 v1 = *(const bf16x8*)(p + 8);
            int s = (dy + 1) * 3 + (dx + 1);
            if (ok) {
                float a = 0.f;
#pragma unroll
                for (int ci = 0; ci < 8; ++ci) a += bf2f(v0[ci]) * W3[ci * 9 + s];
#pragma unroll
                for (int ci = 0; ci < 8; ++ci) a += bf2f(v1[ci]) * W3[(8 + ci) * 9 + s];
                acc += a;
            }
        }
    }
    float sg = 1.f / (1.f + expf(-acc));
    float tf = 0.7f * tgb[i] + 0.3f * sg;
    outb[i] = fminf(fmaxf(tf, 0.f), 1.f);
}

extern "C" void kernel_launch(void* const* d_in, const int* in_sizes, int n_in,
                              void* d_out, int out_size, void* d_ws, size_t ws_size,
                              hipStream_t stream) {
    const float* I    = (const float*)d_in[0];
    const float* t0   = (const float*)d_in[1];
    const float* dark = (const float*)d_in[2];
    const float* A    = (const float*)d_in[3];
    const float* W1   = (const float*)d_in[4];
    const float* b1   = (const float*)d_in[5];
    const float* W2   = (const float*)d_in[6];
    const float* b2   = (const float*)d_in[7];
    const float* W3   = (const float*)d_in[8];
    const float* b3   = (const float*)d_in[9];
    float* out = (float*)d_out;
    float* ws  = (float*)d_ws;

    const size_t P = (size_t)BB * HW;   // 2,097,152 floats = 8 MiB
    // fp32 box-path buffers
    float* g   = ws;            // [0,P)       dead after vbox2_tg
    float* hg  = ws + 1 * P;    // [P,5P)      dead after vbox4_ab
    float* hp  = ws + 2 * P;
    float* hgp = ws + 3 * P;
    float* hgg = ws + 4 * P;
    float* a   = ws + 5 * P;    // [5P,7P)     dead after hbox2
    float* bb  = ws + 6 * P;
    float* ha  = ws + 7 * P;    // [7P,9P)     dead after vbox2_tg
    float* hb  = ws + 8 * P;
    float* tg  = ws + 5 * P;    // reuse a slot (fp32, lives until end)
    // bf16 CNN buffers (overlap dead fp32 regions)
    short* feats = (short*)(ws + 1 * P);   // [B][H][W][8]  bf16 = 4P float-slots
    short* h1    = (short*)(ws + 6 * P);   // per-batch [H][W][32] bf16 = 2P float-slots
    short* h2    = (short*)(ws);           // per-batch [H][W][16] bf16 = 1P float-slots

    k_gray<<<(int)((P + 255) / 256), 256, 0, stream>>>(I, g, (int)P);
    k_hbox4<<<BB * HH, 256, 0, stream>>>(g, t0, hg, hp, hgp, hgg);
    dim3 gv(WW / 256, BB, HH / SEG);
    k_vbox4_ab<<<gv, 256, 0, stream>>>(hg, hp, hgp, hgg, a, bb);
    k_hbox2<<<BB * HH, 256, 0, stream>>>(a, bb, ha, hb);
    k_vbox2_tg<<<gv, 256, 0, stream>>>(ha, hb, g, tg);
    k_feats<<<(int)(P / 256), 256, 0, stream>>>(I, tg, dark, A, feats);

    for (int b = 0; b < BB; ++b) {
        k_conv1_mfma<<<HH * 2, 256, 0, stream>>>(feats + (size_t)b * HW * 8, W1, b1, h1);
        k_conv2_mfma<<<HH * 2, 256, 0, stream>>>(h1, W2, b2, h2);
        k_conv3_final<<<HW / 256, 256, 0, stream>>>(h2, W3, b3, tg + (size_t)b * HW,
                                                    out + (size_t)b * HW);
    }
}

// Round 3
// 445.584 us; speedup vs baseline: 2.8977x; 1.3081x over previous
//
#include <hip/hip_runtime.h>
#include <cmath>

#define BB 8
#define HH 512
#define WW 512
#define HW (HH*WW)
#define RAD 15
#define SEG 16
#define EPS 0.001f
#define INV_K (1.0f/31.0f)

typedef short bf16x8 __attribute__((ext_vector_type(8)));
typedef short bf16x4 __attribute__((ext_vector_type(4)));
typedef float f32x4 __attribute__((ext_vector_type(4)));
typedef float f32x2 __attribute__((ext_vector_type(2)));

static __device__ inline short f2bf(float f) {
    unsigned int u = __float_as_uint(f);
    unsigned int r = (u + 0x7FFFu + ((u >> 16) & 1u)) >> 16;   // RNE
    return (short)r;
}
static __device__ inline float bf2f(short s) {
    return __uint_as_float(((unsigned int)(unsigned short)s) << 16);
}

// ---------------- gray ----------------
__global__ __launch_bounds__(256) void k_gray(const float* __restrict__ I,
                                              float* __restrict__ g) {
    int i = blockIdx.x * 256 + threadIdx.x;
    int b = i >> 18;
    int off = i & (HW - 1);
    const float* Ib = I + (size_t)b * 3 * HW;
    g[i] = 0.299f * Ib[off] + 0.587f * Ib[HW + off] + 0.114f * Ib[2 * HW + off];
}

// ---------------- horizontal box: {g,p,g*p,g*g} -> hq float4 ----------------
__global__ __launch_bounds__(256) void k_hbox4(const float* __restrict__ g,
                                               const float* __restrict__ p,
                                               f32x4* __restrict__ hq) {
    __shared__ float sg[WW], sp[WW];
    int base = blockIdx.x * WW;   // row over B*HH
    int tid = threadIdx.x;
    for (int x = tid; x < WW; x += 256) { sg[x] = g[base + x]; sp[x] = p[base + x]; }
    __syncthreads();
    for (int x = tid; x < WW; x += 256) {
        float s0 = 0.f, s1 = 0.f, s2 = 0.f, s3 = 0.f;
        int lo = x - RAD < 0 ? 0 : x - RAD;
        int hi = x + RAD >= WW ? WW - 1 : x + RAD;
        for (int i = lo; i <= hi; ++i) {
            float gv = sg[i], pv = sp[i];
            s0 += gv; s1 += pv; s2 += gv * pv; s3 += gv * gv;
        }
        f32x4 o = { s0 * INV_K, s1 * INV_K, s2 * INV_K, s3 * INV_K };
        hq[base + x] = o;
    }
}

// ---------------- vertical box of hq, fused a/b -> ab float2 ----------------
__global__ __launch_bounds__(256) void k_vbox4_ab(const f32x4* __restrict__ hq,
                                                  f32x2* __restrict__ ab) {
    int x = blockIdx.x * 256 + threadIdx.x;
    int b = blockIdx.y;
    int y0 = blockIdx.z * SEG;
    int pbase = b * HW + x;
    f32x4 s = { 0.f, 0.f, 0.f, 0.f };
    int r0 = y0 - RAD < 0 ? 0 : y0 - RAD;
    for (int r = r0; r < y0 + RAD; ++r) s += hq[pbase + r * WW];
    for (int y = y0; y < y0 + SEG; ++y) {
        if (y + RAD < HH) s += hq[pbase + (y + RAD) * WW];
        float mI = s[0] * INV_K, mP = s[1] * INV_K, mIp = s[2] * INV_K, mII = s[3] * INV_K;
        float cov = mIp - mI * mP;
        float var = mII - mI * mI;
        float av = cov / (var + EPS);
        float bv = mP - av * mI;
        f32x2 o = { av, bv };
        ab[pbase + y * WW] = o;
        if (y - RAD >= 0) s -= hq[pbase + (y - RAD) * WW];
    }
}

// ---------------- horizontal box of ab -> hab float2 ----------------
__global__ __launch_bounds__(256) void k_hbox2(const f32x2* __restrict__ ab,
                                               f32x2* __restrict__ hab) {
    __shared__ float sa[WW], sb[WW];
    int base = blockIdx.x * WW;
    int tid = threadIdx.x;
    for (int x = tid; x < WW; x += 256) {
        f32x2 v = ab[base + x];
        sa[x] = v[0]; sb[x] = v[1];
    }
    __syncthreads();
    for (int x = tid; x < WW; x += 256) {
        float s0 = 0.f, s1 = 0.f;
        int lo = x - RAD < 0 ? 0 : x - RAD;
        int hi = x + RAD >= WW ? WW - 1 : x + RAD;
        for (int i = lo; i <= hi; ++i) { s0 += sa[i]; s1 += sb[i]; }
        f32x2 o = { s0 * INV_K, s1 * INV_K };
        hab[base + x] = o;
    }
}

// ---------------- vertical box of hab, fused t_guided ----------------
__global__ __launch_bounds__(256) void k_vbox2_tg(const f32x2* __restrict__ hab,
                                                  const float* __restrict__ g,
                                                  float* __restrict__ tg) {
    int x = blockIdx.x * 256 + threadIdx.x;
    int b = blockIdx.y;
    int y0 = blockIdx.z * SEG;
    int pbase = b * HW + x;
    f32x2 s = { 0.f, 0.f };
    int r0 = y0 - RAD < 0 ? 0 : y0 - RAD;
    for (int r = r0; r < y0 + RAD; ++r) s += hab[pbase + r * WW];
    for (int y = y0; y < y0 + SEG; ++y) {
        if (y + RAD < HH) s += hab[pbase + (y + RAD) * WW];
        int o = pbase + y * WW;
        tg[o] = (s[0] * INV_K) * g[o] + (s[1] * INV_K);
        if (y - RAD >= 0) s -= hab[pbase + (y - RAD) * WW];
    }
}

// ---------------- feats: NHWC bf16 [B][H][W][8] ----------------
__global__ __launch_bounds__(256) void k_feats(const float* __restrict__ I,
                                               const float* __restrict__ tg,
                                               const float* __restrict__ dark,
                                               const float* __restrict__ A,
                                               short* __restrict__ feats) {
    int i = blockIdx.x * 256 + threadIdx.x;
    int b = i >> 18;
    int off = i & (HW - 1);
    const float* Ib = I + (size_t)b * 3 * HW;
    bf16x8 v;
    v[0] = f2bf(Ib[off]);
    v[1] = f2bf(Ib[HW + off]);
    v[2] = f2bf(Ib[2 * HW + off]);
    v[3] = f2bf(tg[i]);
    v[4] = f2bf(dark[i]);
    v[5] = f2bf(A[b * 3 + 0]);
    v[6] = f2bf(A[b * 3 + 1]);
    v[7] = f2bf(A[b * 3 + 2]);
    *(bf16x8*)(feats + (size_t)i * 8) = v;
}

// ---------------- conv1 MFMA: feats[.][8] -> h1[.][32], relu ----------------
__global__ __launch_bounds__(256) void k_conv1_mfma(const short* __restrict__ feats,
                                                    const float* __restrict__ W1,
                                                    const float* __restrict__ b1,
                                                    short* __restrict__ h1) {
    int tid = threadIdx.x;
    int lane = tid & 63;
    int wave = tid >> 6;
    int y  = blockIdx.x >> 1;
    int x0 = (blockIdx.x & 1) * 256 + wave * 64;
    int b = blockIdx.y;
    const short* fb = feats + (size_t)b * HW * 8;
    short* h1b = h1 + (size_t)b * HW * 32;
    int j = lane & 15;
    int g = lane >> 4;

    bf16x8 wA[2][3];
#pragma unroll
    for (int cg = 0; cg < 2; ++cg) {
        int co = cg * 16 + j;
#pragma unroll
        for (int t = 0; t < 3; ++t) {
            int s = t * 4 + g;
            bf16x8 w;
#pragma unroll
            for (int i = 0; i < 8; ++i)
                w[i] = (s < 9) ? f2bf(W1[co * 72 + i * 9 + s]) : (short)0;
            wA[cg][t] = w;
        }
    }

    f32x4 acc[2][4] = {};
    bool fast = (y >= 1) && (y <= 509) && (x0 >= 1) && (x0 <= 447);
    if (fast) {
        // s>=9 lanes read dy=2 rows: in-plane (y<=509) and multiplied by zero A.
#pragma unroll
        for (int t = 0; t < 3; ++t) {
            int s = t * 4 + g;
            int dy = s / 3 - 1, dx = s - (s / 3) * 3 - 1;
            const short* rp = fb + ((size_t)(y + dy) * WW + (x0 + j + dx)) * 8;
            bf16x8 Bv[4];
#pragma unroll
            for (int n = 0; n < 4; ++n) Bv[n] = *(const bf16x8*)(rp + n * 128);
#pragma unroll
            for (int cg = 0; cg < 2; ++cg)
#pragma unroll
                for (int n = 0; n < 4; ++n)
                    acc[cg][n] = __builtin_amdgcn_mfma_f32_16x16x32_bf16(wA[cg][t], Bv[n], acc[cg][n], 0, 0, 0);
        }
    } else {
        const bf16x8 zerov = {0,0,0,0,0,0,0,0};
#pragma unroll
        for (int t = 0; t < 3; ++t) {
            int s = t * 4 + g;
            int dy = s / 3 - 1, dx = s - (s / 3) * 3 - 1;
            int yy = y + dy;
            bf16x8 Bv[4];
#pragma unroll
            for (int n = 0; n < 4; ++n) {
                int xx = x0 + n * 16 + j + dx;
                bool ok = (s < 9) && yy >= 0 && yy < HH && xx >= 0 && xx < WW;
                int yc = yy < 0 ? 0 : (yy > HH - 1 ? HH - 1 : yy);
                int xc = xx < 0 ? 0 : (xx > WW - 1 ? WW - 1 : xx);
                bf16x8 v = *(const bf16x8*)(fb + ((size_t)yc * WW + xc) * 8);
                Bv[n] = ok ? v : zerov;
            }
#pragma unroll
            for (int cg = 0; cg < 2; ++cg)
#pragma unroll
                for (int n = 0; n < 4; ++n)
                    acc[cg][n] = __builtin_amdgcn_mfma_f32_16x16x32_bf16(wA[cg][t], Bv[n], acc[cg][n], 0, 0, 0);
        }
    }

#pragma unroll
    for (int cg = 0; cg < 2; ++cg) {
        int co0 = cg * 16 + g * 4;
        float bias[4];
#pragma unroll
        for (int r = 0; r < 4; ++r) bias[r] = b1[co0 + r];
#pragma unroll
        for (int n = 0; n < 4; ++n) {
            int pix = y * WW + x0 + n * 16 + j;
            bf16x4 o;
#pragma unroll
            for (int r = 0; r < 4; ++r) o[r] = f2bf(fmaxf(acc[cg][n][r] + bias[r], 0.f));
            *(bf16x4*)(h1b + (size_t)pix * 32 + co0) = o;
        }
    }
}

// ---------------- conv2 MFMA: h1[.][32] -> h2[.][16], relu ----------------
__global__ __launch_bounds__(256) void k_conv2_mfma(const short* __restrict__ h1,
                                                    const float* __restrict__ W2,
                                                    const float* __restrict__ b2,
                                                    short* __restrict__ h2) {
    int tid = threadIdx.x;
    int lane = tid & 63;
    int wave = tid >> 6;
    int y  = blockIdx.x >> 1;
    int x0 = (blockIdx.x & 1) * 256 + wave * 64;
    int b = blockIdx.y;
    const short* h1b = h1 + (size_t)b * HW * 32;
    short* h2b = h2 + (size_t)b * HW * 16;
    int j = lane & 15;
    int g = lane >> 4;
    int ci0 = g * 8;

    bf16x8 wA[9];
#pragma unroll
    for (int s = 0; s < 9; ++s) {
        bf16x8 w;
#pragma unroll
        for (int i = 0; i < 8; ++i)
            w[i] = f2bf(W2[j * 288 + (ci0 + i) * 9 + s]);
        wA[s] = w;
    }

    f32x4 acc[4] = {};
    bool fast = (y >= 1) && (y <= 510) && (x0 >= 1) && (x0 <= 447);
    if (fast) {
#pragma unroll
        for (int dy = -1; dy <= 1; ++dy) {
            const short* rowp = h1b + (size_t)(y + dy) * WW * 32;
            int s0 = (dy + 1) * 3;
#pragma unroll
            for (int n = 0; n < 4; ++n) {
                const short* pp = rowp + (size_t)(x0 + n * 16 + j) * 32 + ci0;
                bf16x8 vm = *(const bf16x8*)(pp - 32);
                bf16x8 v0 = *(const bf16x8*)(pp);
                bf16x8 vp = *(const bf16x8*)(pp + 32);
                acc[n] = __builtin_amdgcn_mfma_f32_16x16x32_bf16(wA[s0 + 0], vm, acc[n], 0, 0, 0);
                acc[n] = __builtin_amdgcn_mfma_f32_16x16x32_bf16(wA[s0 + 1], v0, acc[n], 0, 0, 0);
                acc[n] = __builtin_amdgcn_mfma_f32_16x16x32_bf16(wA[s0 + 2], vp, acc[n], 0, 0, 0);
            }
        }
    } else {
        const bf16x8 zerov = {0,0,0,0,0,0,0,0};
#pragma unroll
        for (int dy = -1; dy <= 1; ++dy) {
            int yy = y + dy;
            if (yy >= 0 && yy < HH) {
                const short* rowp = h1b + (size_t)yy * WW * 32;
#pragma unroll
                for (int dx = -1; dx <= 1; ++dx) {
                    int s = (dy + 1) * 3 + (dx + 1);
#pragma unroll
                    for (int n = 0; n < 4; ++n) {
                        int xx = x0 + n * 16 + j + dx;
                        bool ok = (xx >= 0) && (xx < WW);
                        int xc = ok ? xx : 0;
                        bf16x8 v = *(const bf16x8*)(rowp + (size_t)xc * 32 + ci0);
                        acc[n] = __builtin_amdgcn_mfma_f32_16x16x32_bf16(wA[s], ok ? v : zerov, acc[n], 0, 0, 0);
                    }
                }
            }
        }
    }

    int co0 = g * 4;
    float bias[4];
#pragma unroll
    for (int r = 0; r < 4; ++r) bias[r] = b2[co0 + r];
#pragma unroll
    for (int n = 0; n < 4; ++n) {
        int pix = y * WW + x0 + n * 16 + j;
        bf16x4 o;
#pragma unroll
        for (int r = 0; r < 4; ++r) o[r] = f2bf(fmaxf(acc[n][r] + bias[r], 0.f));
        *(bf16x4*)(h2b + (size_t)pix * 16 + co0) = o;
    }
}

// ---------------- conv3: h2[.][16] -> 1, sigmoid, blend, clip ----------------
__global__ __launch_bounds__(256) void k_conv3_final(const short* __restrict__ h2,
                                                     const float* __restrict__ W3,
                                                     const float* __restrict__ b3,
                                                     const float* __restrict__ tg,
                                                     float* __restrict__ out) {
    int b = blockIdx.y;
    int i = blockIdx.x * 256 + threadIdx.x;   // pixel in batch
    int y = i >> 9;
    int x = i & (WW - 1);
    const short* h2b = h2 + (size_t)b * HW * 16;
    float acc = b3[0];
    bool fast = (y >= 1) && (y <= 510) && (x >= 1) && (x <= 510);
    if (fast) {
#pragma unroll
        for (int dy = -1; dy <= 1; ++dy) {
            const short* rowp = h2b + ((size_t)(y + dy) * WW + x) * 16;
#pragma unroll
            for (int dx = -1; dx <= 1; ++dx) {
                const short* p = rowp + dx * 16;
                bf16x8 v0 = *(const bf16x8*)(p);
                bf16x8 v1 = *(const bf16x8*)(p + 8);
                int s = (dy + 1) * 3 + (dx + 1);
                float a = 0.f;
#pragma unroll
                for (int ci = 0; ci < 8; ++ci) a += bf2f(v0[ci]) * W3[ci * 9 + s];
#pragma unroll
                for (int ci = 0; ci < 8; ++ci) a += bf2f(v1[ci]) * W3[(8 + ci) * 9 + s];
                acc += a;
            }
        }
    } else {
#pragma unroll
        for (int dy = -1; dy <= 1; ++dy) {
            int yy = y + dy;
            bool yok = (yy >= 0) && (yy < HH);
#pragma unroll
            for (int dx = -1; dx <= 1; ++dx) {
                int xx = x + dx;
                bool ok = yok && xx >= 0 && xx < WW;
                int yc = yy < 0 ? 0 : (yy > HH - 1 ? HH - 1 : yy);
                int xc = xx < 0 ? 0 : (xx > WW - 1 ? WW - 1 : xx);
                const short* p = h2b + ((size_t)yc * WW + xc) * 16;
                bf16x8 v0 = *(const bf16x8*)(p);
                bf16x8 v1 = *(const bf16x8*)(p + 8);
                int s = (dy + 1) * 3 + (dx + 1);
                if (ok) {
                    float a = 0.f;
#pragma unroll
                    for (int ci = 0; ci < 8; ++ci) a += bf2f(v0[ci]) * W3[ci * 9 + s];
#pragma unroll
                    for (int ci = 0; ci < 8; ++ci) a += bf2f(v1[ci]) * W3[(8 + ci) * 9 + s];
                    acc += a;
                }
            }
        }
    }
    float sg = 1.f / (1.f + expf(-acc));
    float tf = 0.7f * tg[(size_t)b * HW + i] + 0.3f * sg;
    out[(size_t)b * HW + i] = fminf(fmaxf(tf, 0.f), 1.f);
}

extern "C" void kernel_launch(void* const* d_in, const int* in_sizes, int n_in,
                              void* d_out, int out_size, void* d_ws, size_t ws_size,
                              hipStream_t stream) {
    const float* I    = (const float*)d_in[0];
    const float* t0   = (const float*)d_in[1];
    const float* dark = (const float*)d_in[2];
    const float* A    = (const float*)d_in[3];
    const float* W1   = (const float*)d_in[4];
    const float* b1   = (const float*)d_in[5];
    const float* W2   = (const float*)d_in[6];
    const float* b2   = (const float*)d_in[7];
    const float* W3   = (const float*)d_in[8];
    const float* b3   = (const float*)d_in[9];
    float* out = (float*)d_out;
    float* ws  = (float*)d_ws;

    const size_t P = (size_t)BB * HW;       // 2M floats = 8 MB
    // persistent across phases:
    float* tg    = ws;                      // [0,P)        fp32
    short* feats = (short*)(ws + P);        // [P,5P)       bf16 x8ch
    short* h1    = (short*)(ws + 5 * P);    // [5P,21P)     bf16 x32ch (all batches)
    short* h2    = (short*)(ws + 21 * P);   // [21P,29P)    bf16 x16ch (all batches)
    // box-path scratch, overlapping h1/h2 (dead before conv1 runs):
    float* g   = ws + 5 * P;                // [5P,6P)
    f32x4* hq  = (f32x4*)(ws + 6 * P);      // [6P,10P)
    f32x2* ab  = (f32x2*)(ws + 10 * P);     // [10P,12P)
    f32x2* hab = (f32x2*)(ws + 12 * P);     // [12P,14P)

    k_gray<<<(int)(P / 256), 256, 0, stream>>>(I, g);
    k_hbox4<<<BB * HH, 256, 0, stream>>>(g, t0, hq);
    dim3 gv(WW / 256, BB, HH / SEG);
    k_vbox4_ab<<<gv, 256, 0, stream>>>(hq, ab);
    k_hbox2<<<BB * HH, 256, 0, stream>>>(ab, hab);
    k_vbox2_tg<<<gv, 256, 0, stream>>>(hab, g, tg);
    k_feats<<<(int)(P / 256), 256, 0, stream>>>(I, tg, dark, A, feats);

    dim3 gc(HH * 2, BB);
    k_conv1_mfma<<<gc, 256, 0, stream>>>(feats, W1, b1, h1);
    k_conv2_mfma<<<gc, 256, 0, stream>>>(h1, W2, b2, h2);
    dim3 g3(HW / 256, BB);
    k_conv3_final<<<g3, 256, 0, stream>>>(h2, W3, b3, tg, out);
}

// Round 4
// 282.216 us; speedup vs baseline: 4.5750x; 1.5789x over previous
//
#include <hip/hip_runtime.h>
#include <cmath>

#define BB 8
#define HH 512
#define WW 512
#define HW (HH*WW)
#define RAD 15
#define SEG 32
#define EPS 0.001f
#define INV_K (1.0f/31.0f)

typedef short bf16x8 __attribute__((ext_vector_type(8)));
typedef short bf16x4 __attribute__((ext_vector_type(4)));
typedef float f32x4 __attribute__((ext_vector_type(4)));
typedef float f32x2 __attribute__((ext_vector_type(2)));

static __device__ inline short f2bf(float f) {
    unsigned int u = __float_as_uint(f);
    unsigned int r = (u + 0x7FFFu + ((u >> 16) & 1u)) >> 16;   // RNE
    return (short)r;
}
static __device__ inline float bf2f(short s) {
    return __uint_as_float(((unsigned int)(unsigned short)s) << 16);
}

// ---------------- weight fragment prepack (1 wave) ----------------
// wf1[(cg*3+t)*64+lane] : A-frag for conv1 k-slice t, co-group cg
// wf2[s*64+lane]        : A-frag for conv2 tap s
__global__ __launch_bounds__(64) void k_wprep(const float* __restrict__ W1,
                                              const float* __restrict__ W2,
                                              short* __restrict__ wf1,
                                              short* __restrict__ wf2) {
    int lane = threadIdx.x;
    int j = lane & 15, g = lane >> 4;
#pragma unroll
    for (int cg = 0; cg < 2; ++cg)
#pragma unroll
        for (int t = 0; t < 3; ++t) {
            int s = t * 4 + g;
            bf16x8 w;
#pragma unroll
            for (int i = 0; i < 8; ++i)
                w[i] = (s < 9) ? f2bf(W1[(cg * 16 + j) * 72 + i * 9 + s]) : (short)0;
            *(bf16x8*)(wf1 + ((cg * 3 + t) * 64 + lane) * 8) = w;
        }
    int ci0 = g * 8;
#pragma unroll
    for (int s = 0; s < 9; ++s) {
        bf16x8 w;
#pragma unroll
        for (int i = 0; i < 8; ++i)
            w[i] = f2bf(W2[j * 288 + (ci0 + i) * 9 + s]);
        *(bf16x8*)(wf2 + (s * 64 + lane) * 8) = w;
    }
}

// ---------------- gray fused with horizontal box: {g,p,g*p,g*g} -> hq ----------------
__global__ __launch_bounds__(256) void k_gray_hbox4(const float* __restrict__ I,
                                                    const float* __restrict__ p,
                                                    float* __restrict__ g,
                                                    f32x4* __restrict__ hq) {
    __shared__ float sg[WW], sp[WW];
    int row = blockIdx.x;            // b*HH + y
    int b = row >> 9;
    int base = row * WW;
    const float* Ib = I + (size_t)b * 3 * HW + (size_t)(row & 511) * WW;
    int tid = threadIdx.x;
    for (int x = tid; x < WW; x += 256) {
        float gv = 0.299f * Ib[x] + 0.587f * Ib[HW + x] + 0.114f * Ib[2 * HW + x];
        sg[x] = gv; sp[x] = p[base + x];
        g[base + x] = gv;
    }
    __syncthreads();
    for (int x = tid; x < WW; x += 256) {
        float s0 = 0.f, s1 = 0.f, s2 = 0.f, s3 = 0.f;
        int lo = x - RAD < 0 ? 0 : x - RAD;
        int hi = x + RAD >= WW ? WW - 1 : x + RAD;
        for (int i = lo; i <= hi; ++i) {
            float gv = sg[i], pv = sp[i];
            s0 += gv; s1 += pv; s2 += gv * pv; s3 += gv * gv;
        }
        f32x4 o = { s0 * INV_K, s1 * INV_K, s2 * INV_K, s3 * INV_K };
        hq[base + x] = o;
    }
}

// ---------------- vertical box of hq, fused a/b -> ab float2 ----------------
__global__ __launch_bounds__(256) void k_vbox4_ab(const f32x4* __restrict__ hq,
                                                  f32x2* __restrict__ ab) {
    int x = blockIdx.x * 256 + threadIdx.x;
    int b = blockIdx.y;
    int y0 = blockIdx.z * SEG;
    int pbase = b * HW + x;
    f32x4 s = { 0.f, 0.f, 0.f, 0.f };
    int r0 = y0 - RAD < 0 ? 0 : y0 - RAD;
    for (int r = r0; r < y0 + RAD; ++r) s += hq[pbase + r * WW];
    for (int y = y0; y < y0 + SEG; ++y) {
        if (y + RAD < HH) s += hq[pbase + (y + RAD) * WW];
        float mI = s[0] * INV_K, mP = s[1] * INV_K, mIp = s[2] * INV_K, mII = s[3] * INV_K;
        float cov = mIp - mI * mP;
        float var = mII - mI * mI;
        float av = cov / (var + EPS);
        float bv = mP - av * mI;
        f32x2 o = { av, bv };
        ab[pbase + y * WW] = o;
        if (y - RAD >= 0) s -= hq[pbase + (y - RAD) * WW];
    }
}

// ---------------- horizontal box of ab -> hab float2 ----------------
__global__ __launch_bounds__(256) void k_hbox2(const f32x2* __restrict__ ab,
                                               f32x2* __restrict__ hab) {
    __shared__ float sa[WW], sb[WW];
    int base = blockIdx.x * WW;
    int tid = threadIdx.x;
    for (int x = tid; x < WW; x += 256) {
        f32x2 v = ab[base + x];
        sa[x] = v[0]; sb[x] = v[1];
    }
    __syncthreads();
    for (int x = tid; x < WW; x += 256) {
        float s0 = 0.f, s1 = 0.f;
        int lo = x - RAD < 0 ? 0 : x - RAD;
        int hi = x + RAD >= WW ? WW - 1 : x + RAD;
        for (int i = lo; i <= hi; ++i) { s0 += sa[i]; s1 += sb[i]; }
        f32x2 o = { s0 * INV_K, s1 * INV_K };
        hab[base + x] = o;
    }
}

// ---------------- vertical box of hab, fused t_guided ----------------
__global__ __launch_bounds__(256) void k_vbox2_tg(const f32x2* __restrict__ hab,
                                                  const float* __restrict__ g,
                                                  float* __restrict__ tg) {
    int x = blockIdx.x * 256 + threadIdx.x;
    int b = blockIdx.y;
    int y0 = blockIdx.z * SEG;
    int pbase = b * HW + x;
    f32x2 s = { 0.f, 0.f };
    int r0 = y0 - RAD < 0 ? 0 : y0 - RAD;
    for (int r = r0; r < y0 + RAD; ++r) s += hab[pbase + r * WW];
    for (int y = y0; y < y0 + SEG; ++y) {
        if (y + RAD < HH) s += hab[pbase + (y + RAD) * WW];
        int o = pbase + y * WW;
        tg[o] = (s[0] * INV_K) * g[o] + (s[1] * INV_K);
        if (y - RAD >= 0) s -= hab[pbase + (y - RAD) * WW];
    }
}

// ---------------- feats: NHWC bf16 [B][H][W][8] ----------------
__global__ __launch_bounds__(256) void k_feats(const float* __restrict__ I,
                                               const float* __restrict__ tg,
                                               const float* __restrict__ dark,
                                               const float* __restrict__ A,
                                               short* __restrict__ feats) {
    int i = blockIdx.x * 256 + threadIdx.x;
    int b = i >> 18;
    int off = i & (HW - 1);
    const float* Ib = I + (size_t)b * 3 * HW;
    bf16x8 v;
    v[0] = f2bf(Ib[off]);
    v[1] = f2bf(Ib[HW + off]);
    v[2] = f2bf(Ib[2 * HW + off]);
    v[3] = f2bf(tg[i]);
    v[4] = f2bf(dark[i]);
    v[5] = f2bf(A[b * 3 + 0]);
    v[6] = f2bf(A[b * 3 + 1]);
    v[7] = f2bf(A[b * 3 + 2]);
    *(bf16x8*)(feats + (size_t)i * 8) = v;
}

// ---------------- conv1 MFMA: feats[.][8] -> h1[.][32], relu ----------------
__global__ __launch_bounds__(256) void k_conv1_mfma(const short* __restrict__ feats,
                                                    const short* __restrict__ wf1,
                                                    const float* __restrict__ b1,
                                                    short* __restrict__ h1) {
    int tid = threadIdx.x;
    int lane = tid & 63;
    int wave = tid >> 6;
    int y  = blockIdx.x >> 1;
    int x0 = (blockIdx.x & 1) * 256 + wave * 64;
    int b = blockIdx.y;
    const short* fb = feats + (size_t)b * HW * 8;
    short* h1b = h1 + (size_t)b * HW * 32;
    int j = lane & 15;
    int g = lane >> 4;

    const bf16x8* wf1v = (const bf16x8*)wf1;
    bf16x8 wA[2][3];
#pragma unroll
    for (int cg = 0; cg < 2; ++cg)
#pragma unroll
        for (int t = 0; t < 3; ++t)
            wA[cg][t] = wf1v[(cg * 3 + t) * 64 + lane];

    f32x4 acc[2][4] = {};
    bool fast = (y >= 1) && (y <= 509) && (x0 >= 1) && (x0 <= 447);
    if (fast) {
        // s>=9 lanes read dy=2 rows: in-plane (y<=509) and multiplied by zero A.
#pragma unroll
        for (int t = 0; t < 3; ++t) {
            int s = t * 4 + g;
            int dy = s / 3 - 1, dx = s - (s / 3) * 3 - 1;
            const short* rp = fb + ((size_t)(y + dy) * WW + (x0 + j + dx)) * 8;
            bf16x8 Bv[4];
#pragma unroll
            for (int n = 0; n < 4; ++n) Bv[n] = *(const bf16x8*)(rp + n * 128);
#pragma unroll
            for (int cg = 0; cg < 2; ++cg)
#pragma unroll
                for (int n = 0; n < 4; ++n)
                    acc[cg][n] = __builtin_amdgcn_mfma_f32_16x16x32_bf16(wA[cg][t], Bv[n], acc[cg][n], 0, 0, 0);
        }
    } else {
        const bf16x8 zerov = {0,0,0,0,0,0,0,0};
#pragma unroll
        for (int t = 0; t < 3; ++t) {
            int s = t * 4 + g;
            int dy = s / 3 - 1, dx = s - (s / 3) * 3 - 1;
            int yy = y + dy;
            bf16x8 Bv[4];
#pragma unroll
            for (int n = 0; n < 4; ++n) {
                int xx = x0 + n * 16 + j + dx;
                bool ok = (s < 9) && yy >= 0 && yy < HH && xx >= 0 && xx < WW;
                int yc = yy < 0 ? 0 : (yy > HH - 1 ? HH - 1 : yy);
                int xc = xx < 0 ? 0 : (xx > WW - 1 ? WW - 1 : xx);
                bf16x8 v = *(const bf16x8*)(fb + ((size_t)yc * WW + xc) * 8);
                Bv[n] = ok ? v : zerov;
            }
#pragma unroll
            for (int cg = 0; cg < 2; ++cg)
#pragma unroll
                for (int n = 0; n < 4; ++n)
                    acc[cg][n] = __builtin_amdgcn_mfma_f32_16x16x32_bf16(wA[cg][t], Bv[n], acc[cg][n], 0, 0, 0);
        }
    }

#pragma unroll
    for (int cg = 0; cg < 2; ++cg) {
        int co0 = cg * 16 + g * 4;
        f32x4 bias = *(const f32x4*)(b1 + co0);
#pragma unroll
        for (int n = 0; n < 4; ++n) {
            int pix = y * WW + x0 + n * 16 + j;
            bf16x4 o;
#pragma unroll
            for (int r = 0; r < 4; ++r) o[r] = f2bf(fmaxf(acc[cg][n][r] + bias[r], 0.f));
            *(bf16x4*)(h1b + (size_t)pix * 32 + co0) = o;
        }
    }
}

// ---------------- conv2 MFMA: h1[.][32] -> h2[.][16], relu ----------------
__global__ __launch_bounds__(256) void k_conv2_mfma(const short* __restrict__ h1,
                                                    const short* __restrict__ wf2,
                                                    const float* __restrict__ b2,
                                                    short* __restrict__ h2) {
    int tid = threadIdx.x;
    int lane = tid & 63;
    int wave = tid >> 6;
    int y  = blockIdx.x >> 1;
    int x0 = (blockIdx.x & 1) * 256 + wave * 64;
    int b = blockIdx.y;
    const short* h1b = h1 + (size_t)b * HW * 32;
    short* h2b = h2 + (size_t)b * HW * 16;
    int j = lane & 15;
    int g = lane >> 4;
    int ci0 = g * 8;

    const bf16x8* wf2v = (const bf16x8*)wf2;
    bf16x8 wA[9];
#pragma unroll
    for (int s = 0; s < 9; ++s) wA[s] = wf2v[s * 64 + lane];

    f32x4 acc[4] = {};
    bool fast = (y >= 1) && (y <= 510) && (x0 >= 1) && (x0 <= 447);
    if (fast) {
#pragma unroll
        for (int dy = -1; dy <= 1; ++dy) {
            const short* rowp = h1b + (size_t)(y + dy) * WW * 32;
            int s0 = (dy + 1) * 3;
#pragma unroll
            for (int n = 0; n < 4; ++n) {
                const short* pp = rowp + (size_t)(x0 + n * 16 + j) * 32 + ci0;
                bf16x8 vm = *(const bf16x8*)(pp - 32);
                bf16x8 v0 = *(const bf16x8*)(pp);
                bf16x8 vp = *(const bf16x8*)(pp + 32);
                acc[n] = __builtin_amdgcn_mfma_f32_16x16x32_bf16(wA[s0 + 0], vm, acc[n], 0, 0, 0);
                acc[n] = __builtin_amdgcn_mfma_f32_16x16x32_bf16(wA[s0 + 1], v0, acc[n], 0, 0, 0);
                acc[n] = __builtin_amdgcn_mfma_f32_16x16x32_bf16(wA[s0 + 2], vp, acc[n], 0, 0, 0);
            }
        }
    } else {
        const bf16x8 zerov = {0,0,0,0,0,0,0,0};
#pragma unroll
        for (int dy = -1; dy <= 1; ++dy) {
            int yy = y + dy;
            if (yy >= 0 && yy < HH) {
                const short* rowp = h1b + (size_t)yy * WW * 32;
#pragma unroll
                for (int dx = -1; dx <= 1; ++dx) {
                    int s = (dy + 1) * 3 + (dx + 1);
#pragma unroll
                    for (int n = 0; n < 4; ++n) {
                        int xx = x0 + n * 16 + j + dx;
                        bool ok = (xx >= 0) && (xx < WW);
                        int xc = ok ? xx : 0;
                        bf16x8 v = *(const bf16x8*)(rowp + (size_t)xc * 32 + ci0);
                        acc[n] = __builtin_amdgcn_mfma_f32_16x16x32_bf16(wA[s], ok ? v : zerov, acc[n], 0, 0, 0);
                    }
                }
            }
        }
    }

    int co0 = g * 4;
    f32x4 bias = *(const f32x4*)(b2 + co0);
#pragma unroll
    for (int n = 0; n < 4; ++n) {
        int pix = y * WW + x0 + n * 16 + j;
        bf16x4 o;
#pragma unroll
        for (int r = 0; r < 4; ++r) o[r] = f2bf(fmaxf(acc[n][r] + bias[r], 0.f));
        *(bf16x4*)(h2b + (size_t)pix * 16 + co0) = o;
    }
}

// ---------------- conv3: h2[.][16] -> 1, sigmoid, blend, clip ----------------
__global__ __launch_bounds__(256) void k_conv3_final(const short* __restrict__ h2,
                                                     const float* __restrict__ W3,
                                                     const float* __restrict__ b3,
                                                     const float* __restrict__ tg,
                                                     float* __restrict__ out) {
    int b = blockIdx.y;
    int i = blockIdx.x * 256 + threadIdx.x;   // pixel in batch
    int y = i >> 9;
    int x = i & (WW - 1);
    const short* h2b = h2 + (size_t)b * HW * 16;
    float acc = b3[0];
    bool fast = (y >= 1) && (y <= 510) && (x >= 1) && (x <= 510);
    if (fast) {
#pragma unroll
        for (int dy = -1; dy <= 1; ++dy) {
            const short* rowp = h2b + ((size_t)(y + dy) * WW + x) * 16;
#pragma unroll
            for (int dx = -1; dx <= 1; ++dx) {
                const short* p = rowp + dx * 16;
                bf16x8 v0 = *(const bf16x8*)(p);
                bf16x8 v1 = *(const bf16x8*)(p + 8);
                int s = (dy + 1) * 3 + (dx + 1);
                float a = 0.f;
#pragma unroll
                for (int ci = 0; ci < 8; ++ci) a += bf2f(v0[ci]) * W3[ci * 9 + s];
#pragma unroll
                for (int ci = 0; ci < 8; ++ci) a += bf2f(v1[ci]) * W3[(8 + ci) * 9 + s];
                acc += a;
            }
        }
    } else {
#pragma unroll
        for (int dy = -1; dy <= 1; ++dy) {
            int yy = y + dy;
            bool yok = (yy >= 0) && (yy < HH);
#pragma unroll
            for (int dx = -1; dx <= 1; ++dx) {
                int xx = x + dx;
                bool ok = yok && xx >= 0 && xx < WW;
                int yc = yy < 0 ? 0 : (yy > HH - 1 ? HH - 1 : yy);
                int xc = xx < 0 ? 0 : (xx > WW - 1 ? WW - 1 : xx);
                const short* p = h2b + ((size_t)yc * WW + xc) * 16;
                bf16x8 v0 = *(const bf16x8*)(p);
                bf16x8 v1 = *(const bf16x8*)(p + 8);
                int s = (dy + 1) * 3 + (dx + 1);
                if (ok) {
                    float a = 0.f;
#pragma unroll
                    for (int ci = 0; ci < 8; ++ci) a += bf2f(v0[ci]) * W3[ci * 9 + s];
#pragma unroll
                    for (int ci = 0; ci < 8; ++ci) a += bf2f(v1[ci]) * W3[(8 + ci) * 9 + s];
                    acc += a;
                }
            }
        }
    }
    float sg = 1.f / (1.f + expf(-acc));
    float tf = 0.7f * tg[(size_t)b * HW + i] + 0.3f * sg;
    out[(size_t)b * HW + i] = fminf(fmaxf(tf, 0.f), 1.f);
}

extern "C" void kernel_launch(void* const* d_in, const int* in_sizes, int n_in,
                              void* d_out, int out_size, void* d_ws, size_t ws_size,
                              hipStream_t stream) {
    const float* I    = (const float*)d_in[0];
    const float* t0   = (const float*)d_in[1];
    const float* dark = (const float*)d_in[2];
    const float* A    = (const float*)d_in[3];
    const float* W1   = (const float*)d_in[4];
    const float* b1   = (const float*)d_in[5];
    const float* W2   = (const float*)d_in[6];
    const float* b2   = (const float*)d_in[7];
    const float* W3   = (const float*)d_in[8];
    const float* b3   = (const float*)d_in[9];
    float* out = (float*)d_out;
    float* ws  = (float*)d_ws;

    const size_t P = (size_t)BB * HW;       // 2M floats = 8 MB
    // persistent across phases:
    float* tg    = ws;                      // [0,P)        fp32
    short* feats = (short*)(ws + P);        // [P,5P)       bf16 x8ch
    short* h1    = (short*)(ws + 5 * P);    // [5P,21P)     bf16 x32ch (all batches)
    short* h2    = (short*)(ws + 21 * P);   // [21P,29P)    bf16 x16ch (all batches)
    short* wf1   = (short*)(ws + 29 * P);   // 6*64*8 bf16 = 3072 shorts
    short* wf2   = wf1 + 6 * 64 * 8;        // 9*64*8 bf16 = 4608 shorts
    // box-path scratch, overlapping h1/h2 (dead before conv1 runs):
    float* g   = ws + 5 * P;                // [5P,6P)
    f32x4* hq  = (f32x4*)(ws + 6 * P);      // [6P,10P)
    f32x2* ab  = (f32x2*)(ws + 10 * P);     // [10P,12P)
    f32x2* hab = (f32x2*)(ws + 12 * P);     // [12P,14P)

    k_wprep<<<1, 64, 0, stream>>>(W1, W2, wf1, wf2);
    k_gray_hbox4<<<BB * HH, 256, 0, stream>>>(I, t0, g, hq);
    dim3 gv(WW / 256, BB, HH / SEG);
    k_vbox4_ab<<<gv, 256, 0, stream>>>(hq, ab);
    k_hbox2<<<BB * HH, 256, 0, stream>>>(ab, hab);
    k_vbox2_tg<<<gv, 256, 0, stream>>>(hab, g, tg);
    k_feats<<<(int)(P / 256), 256, 0, stream>>>(I, tg, dark, A, feats);

    dim3 gc(HH * 2, BB);
    k_conv1_mfma<<<gc, 256, 0, stream>>>(feats, wf1, b1, h1);
    k_conv2_mfma<<<gc, 256, 0, stream>>>(h1, wf2, b2, h2);
    dim3 g3(HW / 256, BB);
    k_conv3_final<<<g3, 256, 0, stream>>>(h2, W3, b3, tg, out);
}

// Round 5
// 223.844 us; speedup vs baseline: 5.7681x; 1.2608x over previous
//
#include <hip/hip_runtime.h>
#include <cmath>

#define BB 8
#define HH 512
#define WW 512
#define HW (HH*WW)
#define RAD 15
#define SEG 32
#define EPS 0.001f
#define INV_K (1.0f/31.0f)
#define TROWS 16

typedef short bf16x8 __attribute__((ext_vector_type(8)));
typedef short bf16x4 __attribute__((ext_vector_type(4)));
typedef float f32x4 __attribute__((ext_vector_type(4)));
typedef float f32x2 __attribute__((ext_vector_type(2)));
typedef int   i32x4 __attribute__((ext_vector_type(4)));

static __device__ inline short f2bf(float f) {
    unsigned int u = __float_as_uint(f);
    unsigned int r = (u + 0x7FFFu + ((u >> 16) & 1u)) >> 16;   // RNE
    return (short)r;
}
static __device__ inline float bf2f(short s) {
    return __uint_as_float(((unsigned int)(unsigned short)s) << 16);
}
static __device__ inline int s3(int r) { return (r + 3) % 3; }   // r >= -3

// ---------------- weight fragment prepack (1 wave) ----------------
__global__ __launch_bounds__(64) void k_wprep(const float* __restrict__ W1,
                                              const float* __restrict__ W2,
                                              short* __restrict__ wf1,
                                              short* __restrict__ wf2) {
    int lane = threadIdx.x;
    int j = lane & 15, g = lane >> 4;
#pragma unroll
    for (int cg = 0; cg < 2; ++cg)
#pragma unroll
        for (int t = 0; t < 3; ++t) {
            int s = t * 4 + g;
            bf16x8 w;
#pragma unroll
            for (int i = 0; i < 8; ++i)
                w[i] = (s < 9) ? f2bf(W1[(cg * 16 + j) * 72 + i * 9 + s]) : (short)0;
            *(bf16x8*)(wf1 + ((cg * 3 + t) * 64 + lane) * 8) = w;
        }
    int ci0 = g * 8;
#pragma unroll
    for (int s = 0; s < 9; ++s) {
        bf16x8 w;
#pragma unroll
        for (int i = 0; i < 8; ++i)
            w[i] = f2bf(W2[j * 288 + (ci0 + i) * 9 + s]);
        *(bf16x8*)(wf2 + (s * 64 + lane) * 8) = w;
    }
}

// ------- gray + horizontal box + feats(ch0-2,4-7) -------
__global__ __launch_bounds__(256) void k_gray_hbox4(const float* __restrict__ I,
                                                    const float* __restrict__ p,
                                                    const float* __restrict__ dark,
                                                    const float* __restrict__ A,
                                                    float* __restrict__ g,
                                                    f32x4* __restrict__ hq,
                                                    short* __restrict__ feats) {
    __shared__ float sg[WW], sp[WW];
    int row = blockIdx.x;            // b*HH + y
    int b = row >> 9;
    int base = row * WW;
    const float* Ib = I + (size_t)b * 3 * HW + (size_t)(row & 511) * WW;
    const float* db = dark + (size_t)base;
    short A0 = f2bf(A[b * 3 + 0]), A1 = f2bf(A[b * 3 + 1]), A2 = f2bf(A[b * 3 + 2]);
    int tid = threadIdx.x;
    for (int x = tid; x < WW; x += 256) {
        float i0 = Ib[x], i1 = Ib[HW + x], i2 = Ib[2 * HW + x];
        float gv = 0.299f * i0 + 0.587f * i1 + 0.114f * i2;
        sg[x] = gv; sp[x] = p[base + x];
        g[base + x] = gv;
        bf16x8 v;
        v[0] = f2bf(i0); v[1] = f2bf(i1); v[2] = f2bf(i2);
        v[3] = 0;                       // tg written later by k_vbox2_tg
        v[4] = f2bf(db[x]);
        v[5] = A0; v[6] = A1; v[7] = A2;
        *(bf16x8*)(feats + ((size_t)base + x) * 8) = v;
    }
    __syncthreads();
    for (int x = tid; x < WW; x += 256) {
        float s0 = 0.f, s1 = 0.f, s2 = 0.f, s3v = 0.f;
        int lo = x - RAD < 0 ? 0 : x - RAD;
        int hi = x + RAD >= WW ? WW - 1 : x + RAD;
        for (int i = lo; i <= hi; ++i) {
            float gv = sg[i], pv = sp[i];
            s0 += gv; s1 += pv; s2 += gv * pv; s3v += gv * gv;
        }
        f32x4 o = { s0 * INV_K, s1 * INV_K, s2 * INV_K, s3v * INV_K };
        hq[base + x] = o;
    }
}

// ---------------- vertical box of hq, fused a/b ----------------
__global__ __launch_bounds__(256) void k_vbox4_ab(const f32x4* __restrict__ hq,
                                                  f32x2* __restrict__ ab) {
    int x = blockIdx.x * 256 + threadIdx.x;
    int b = blockIdx.y;
    int y0 = blockIdx.z * SEG;
    int pbase = b * HW + x;
    f32x4 s = { 0.f, 0.f, 0.f, 0.f };
    int r0 = y0 - RAD < 0 ? 0 : y0 - RAD;
    for (int r = r0; r < y0 + RAD; ++r) s += hq[pbase + r * WW];
    for (int y = y0; y < y0 + SEG; ++y) {
        if (y + RAD < HH) s += hq[pbase + (y + RAD) * WW];
        float mI = s[0] * INV_K, mP = s[1] * INV_K, mIp = s[2] * INV_K, mII = s[3] * INV_K;
        float cov = mIp - mI * mP;
        float var = mII - mI * mI;
        float av = cov / (var + EPS);
        float bv = mP - av * mI;
        f32x2 o = { av, bv };
        ab[pbase + y * WW] = o;
        if (y - RAD >= 0) s -= hq[pbase + (y - RAD) * WW];
    }
}

// ---------------- horizontal box of ab ----------------
__global__ __launch_bounds__(256) void k_hbox2(const f32x2* __restrict__ ab,
                                               f32x2* __restrict__ hab) {
    __shared__ float sa[WW], sb[WW];
    int base = blockIdx.x * WW;
    int tid = threadIdx.x;
    for (int x = tid; x < WW; x += 256) {
        f32x2 v = ab[base + x];
        sa[x] = v[0]; sb[x] = v[1];
    }
    __syncthreads();
    for (int x = tid; x < WW; x += 256) {
        float s0 = 0.f, s1 = 0.f;
        int lo = x - RAD < 0 ? 0 : x - RAD;
        int hi = x + RAD >= WW ? WW - 1 : x + RAD;
        for (int i = lo; i <= hi; ++i) { s0 += sa[i]; s1 += sb[i]; }
        f32x2 o = { s0 * INV_K, s1 * INV_K };
        hab[base + x] = o;
    }
}

// ------- vertical box of hab + t_guided -> tg fp32 + feats ch3 -------
__global__ __launch_bounds__(256) void k_vbox2_tg(const f32x2* __restrict__ hab,
                                                  const float* __restrict__ g,
                                                  float* __restrict__ tg,
                                                  short* __restrict__ feats) {
    int x = blockIdx.x * 256 + threadIdx.x;
    int b = blockIdx.y;
    int y0 = blockIdx.z * SEG;
    int pbase = b * HW + x;
    f32x2 s = { 0.f, 0.f };
    int r0 = y0 - RAD < 0 ? 0 : y0 - RAD;
    for (int r = r0; r < y0 + RAD; ++r) s += hab[pbase + r * WW];
    for (int y = y0; y < y0 + SEG; ++y) {
        if (y + RAD < HH) s += hab[pbase + (y + RAD) * WW];
        int o = pbase + y * WW;
        float val = (s[0] * INV_K) * g[o] + (s[1] * INV_K);
        tg[o] = val;
        feats[(size_t)o * 8 + 3] = f2bf(val);
        if (y - RAD >= 0) s -= hab[pbase + (y - RAD) * WW];
    }
}

// ---------------- fused conv1+conv2+conv3 ----------------
// LDS swizzle helpers: h1 row = [512 px][32 ch] bf16, 16B slots XOR'd with px&3.
static __device__ inline bf16x8 ld_h1(const short* hrow, int xx, int gq) {
    int sp = gq ^ (xx & 3);
    return *(const bf16x8*)(hrow + xx * 32 + sp * 8);
}
static __device__ inline void st_h1(short* hrow, int px, int co0, bf16x4 o) {
    int u = co0 >> 2;                 // 8B unit
    int sp = (u >> 1) ^ (px & 3);
    *(bf16x4*)(hrow + px * 32 + sp * 8 + (u & 1) * 4) = o;
}
static __device__ inline void st_h2(short* hrow, int px, int gq, bf16x4 o) {
    int sp = (gq >> 1) ^ (px & 1);
    *(bf16x4*)(hrow + px * 16 + sp * 8 + (gq & 1) * 4) = o;
}

__global__ __launch_bounds__(512, 2) void k_cnn_fused(const short* __restrict__ feats,
                                                      const short* __restrict__ wf1,
                                                      const short* __restrict__ wf2,
                                                      const float* __restrict__ b1,
                                                      const float* __restrict__ b2,
                                                      const float* __restrict__ W3,
                                                      const float* __restrict__ b3,
                                                      const float* __restrict__ tg,
                                                      float* __restrict__ out) {
    __shared__ short h1s[3][512 * 32];   // 96 KB
    __shared__ short h2s[3][512 * 16];   // 48 KB
    __shared__ float w3s[145];

    int tid = threadIdx.x;
    int lane = tid & 63, wave = tid >> 6;
    int j = lane & 15, gq = lane >> 4;
    int b = blockIdx.y;
    int y0 = blockIdx.x * TROWS;
    const short* fb = feats + (size_t)b * HW * 8;
    const float* tgb = tg + (size_t)b * HW;
    float* outb = out + (size_t)b * HW;

    const bf16x8* wf1v = (const bf16x8*)wf1;
    const bf16x8* wf2v = (const bf16x8*)wf2;
    bf16x8 wA1[2][3], wA2[9];
#pragma unroll
    for (int cg = 0; cg < 2; ++cg)
#pragma unroll
        for (int t = 0; t < 3; ++t) wA1[cg][t] = wf1v[(cg * 3 + t) * 64 + lane];
#pragma unroll
    for (int s = 0; s < 9; ++s) wA2[s] = wf2v[s * 64 + lane];
    f32x4 bias1[2];
    bias1[0] = *(const f32x4*)(b1 + gq * 4);
    bias1[1] = *(const f32x4*)(b1 + 16 + gq * 4);
    f32x4 bias2 = *(const f32x4*)(b2 + gq * 4);
    if (tid < 144) w3s[tid] = W3[tid];
    if (tid == 144) w3s[144] = b3[0];
    __syncthreads();

    int xw = wave * 64;
    bool xedge = (wave == 0) || (wave == 7);
    const bf16x8 zerov = {0, 0, 0, 0, 0, 0, 0, 0};

    bf16x8 Bv[3][4];
    bool h1zero = false;

    for (int i = 0; i < TROWS + 5; ++i) {
        int r1 = y0 + i - 2;              // h1 row to compute this iter
        int r2 = y0 + i - 4;              // h2 row
        int r3 = y0 + i - 5;              // out row
        bool do_h1 = (i <= TROWS + 3);
        bool do_h2 = (i >= 3) && (i <= TROWS + 4);
        bool do_out = (i >= 5);

        // ---- P1a: issue feats global loads for h1 row r1 ----
        if (do_h1) {
            h1zero = (r1 < 0) || (r1 > 511);
            if (!h1zero) {
                if (!xedge && r1 >= 1 && r1 <= 509) {
#pragma unroll
                    for (int t = 0; t < 3; ++t) {
                        int s = t * 4 + gq;
                        int dy = s / 3 - 1, dx = s - (s / 3) * 3 - 1;
                        const short* rp = fb + ((size_t)(r1 + dy) * WW + (xw + j + dx)) * 8;
#pragma unroll
                        for (int n = 0; n < 4; ++n)
                            Bv[t][n] = *(const bf16x8*)(rp + n * 128);
                    }
                } else {
#pragma unroll
                    for (int t = 0; t < 3; ++t) {
                        int s = t * 4 + gq;
                        int dy = s / 3 - 1, dx = s - (s / 3) * 3 - 1;
                        int yy = r1 + dy;
#pragma unroll
                        for (int n = 0; n < 4; ++n) {
                            int xx = xw + n * 16 + j + dx;
                            bool ok = (s < 9) && yy >= 0 && yy < HH && xx >= 0 && xx < WW;
                            int yc = yy < 0 ? 0 : (yy > HH - 1 ? HH - 1 : yy);
                            int xc = xx < 0 ? 0 : (xx > WW - 1 ? WW - 1 : xx);
                            bf16x8 v = *(const bf16x8*)(fb + ((size_t)yc * WW + xc) * 8);
                            Bv[t][n] = ok ? v : zerov;
                        }
                    }
                }
            }
        }

        // ---- P1b: conv2 producing h2 row r2 (reads h1 rows r2-1..r2+1) ----
        if (do_h2) {
            short* h2row = h2s[s3(r2)];
            if (r2 < 0 || r2 > 511) {
                i32x4 z = {0, 0, 0, 0};
                ((i32x4*)h2row)[tid * 2 + 0] = z;
                ((i32x4*)h2row)[tid * 2 + 1] = z;
            } else {
                f32x4 acc[4] = {};
#pragma unroll
                for (int dy = 0; dy < 3; ++dy) {
                    const short* hrow = h1s[s3(r2 - 1 + dy)];
                    int st = dy * 3;
                    if (!xedge) {
#pragma unroll
                        for (int n = 0; n < 4; ++n) {
                            int px = xw + n * 16 + j;
                            bf16x8 vm = ld_h1(hrow, px - 1, gq);
                            bf16x8 v0 = ld_h1(hrow, px, gq);
                            bf16x8 vp = ld_h1(hrow, px + 1, gq);
                            acc[n] = __builtin_amdgcn_mfma_f32_16x16x32_bf16(wA2[st + 0], vm, acc[n], 0, 0, 0);
                            acc[n] = __builtin_amdgcn_mfma_f32_16x16x32_bf16(wA2[st + 1], v0, acc[n], 0, 0, 0);
                            acc[n] = __builtin_amdgcn_mfma_f32_16x16x32_bf16(wA2[st + 2], vp, acc[n], 0, 0, 0);
                        }
                    } else {
#pragma unroll
                        for (int n = 0; n < 4; ++n) {
                            int px = xw + n * 16 + j;
#pragma unroll
                            for (int dx = 0; dx < 3; ++dx) {
                                int xx = px + dx - 1;
                                bool ok = (xx >= 0) && (xx < WW);
                                int xc = ok ? xx : 0;
                                bf16x8 v = ld_h1(hrow, xc, gq);
                                acc[n] = __builtin_amdgcn_mfma_f32_16x16x32_bf16(wA2[st + dx], ok ? v : zerov, acc[n], 0, 0, 0);
                            }
                        }
                    }
                }
#pragma unroll
                for (int n = 0; n < 4; ++n) {
                    int px = xw + n * 16 + j;
                    bf16x4 o;
#pragma unroll
                    for (int r = 0; r < 4; ++r) o[r] = f2bf(fmaxf(acc[n][r] + bias2[r], 0.f));
                    st_h2(h2row, px, gq, o);
                }
            }
        }
        __syncthreads();

        // ---- P2a: conv1 MFMA + store h1 row r1 ----
        if (do_h1) {
            short* h1row = h1s[s3(r1)];
            if (h1zero) {
                i32x4 z = {0, 0, 0, 0};
#pragma unroll
                for (int q = 0; q < 4; ++q) ((i32x4*)h1row)[tid * 4 + q] = z;
            } else {
                f32x4 acc[2][4] = {};
#pragma unroll
                for (int t = 0; t < 3; ++t)
#pragma unroll
                    for (int cg = 0; cg < 2; ++cg)
#pragma unroll
                        for (int n = 0; n < 4; ++n)
                            acc[cg][n] = __builtin_amdgcn_mfma_f32_16x16x32_bf16(wA1[cg][t], Bv[t][n], acc[cg][n], 0, 0, 0);
#pragma unroll
                for (int cg = 0; cg < 2; ++cg) {
                    int co0 = cg * 16 + gq * 4;
#pragma unroll
                    for (int n = 0; n < 4; ++n) {
                        int px = xw + n * 16 + j;
                        bf16x4 o;
#pragma unroll
                        for (int r = 0; r < 4; ++r) o[r] = f2bf(fmaxf(acc[cg][n][r] + bias1[cg][r], 0.f));
                        st_h1(h1row, px, co0, o);
                    }
                }
            }
        }

        // ---- P2b: conv3 + sigmoid + blend + clip, out row r3 ----
        if (do_out) {
            int px = tid;
            float acc = w3s[144];
#pragma unroll
            for (int dy = 0; dy < 3; ++dy) {
                const short* hrow = h2s[s3(r3 - 1 + dy)];
#pragma unroll
                for (int dx = 0; dx < 3; ++dx) {
                    int xx = px + dx - 1;
                    bool ok = (xx >= 0) && (xx < WW);
                    int xc = ok ? xx : 0;
                    bf16x8 lo = *(const bf16x8*)(hrow + xc * 16 + (xc & 1) * 8);
                    bf16x8 hi = *(const bf16x8*)(hrow + xc * 16 + (1 - (xc & 1)) * 8);
                    if (ok) {
                        int s = dy * 3 + dx;
                        float a = 0.f;
#pragma unroll
                        for (int ci = 0; ci < 8; ++ci) a += bf2f(lo[ci]) * w3s[ci * 9 + s];
#pragma unroll
                        for (int ci = 0; ci < 8; ++ci) a += bf2f(hi[ci]) * w3s[(8 + ci) * 9 + s];
                        acc += a;
                    }
                }
            }
            float sg = 1.f / (1.f + expf(-acc));
            int o = r3 * WW + px;
            float tf = 0.7f * tgb[o] + 0.3f * sg;
            outb[o] = fminf(fmaxf(tf, 0.f), 1.f);
        }
        __syncthreads();
    }
}

extern "C" void kernel_launch(void* const* d_in, const int* in_sizes, int n_in,
                              void* d_out, int out_size, void* d_ws, size_t ws_size,
                              hipStream_t stream) {
    const float* I    = (const float*)d_in[0];
    const float* t0   = (const float*)d_in[1];
    const float* dark = (const float*)d_in[2];
    const float* A    = (const float*)d_in[3];
    const float* W1   = (const float*)d_in[4];
    const float* b1   = (const float*)d_in[5];
    const float* W2   = (const float*)d_in[6];
    const float* b2   = (const float*)d_in[7];
    const float* W3   = (const float*)d_in[8];
    const float* b3   = (const float*)d_in[9];
    float* out = (float*)d_out;
    float* ws  = (float*)d_ws;

    const size_t P = (size_t)BB * HW;       // 2M floats = 8 MB
    float* tg    = ws;                      // [0,P)   fp32
    short* feats = (short*)(ws + P);        // [P,5P)  bf16 [B][H][W][8]
    float* g     = ws + 5 * P;              // [5P,6P)
    f32x4* hq    = (f32x4*)(ws + 6 * P);    // [6P,10P)
    f32x2* ab    = (f32x2*)(ws + 10 * P);   // [10P,12P)
    f32x2* hab   = (f32x2*)(ws + 12 * P);   // [12P,14P)
    short* wf1   = (short*)(ws + 14 * P);   // 3072 shorts
    short* wf2   = wf1 + 6 * 64 * 8;        // 4608 shorts

    k_wprep<<<1, 64, 0, stream>>>(W1, W2, wf1, wf2);
    k_gray_hbox4<<<BB * HH, 256, 0, stream>>>(I, t0, dark, A, g, hq, feats);
    dim3 gv(WW / 256, BB, HH / SEG);
    k_vbox4_ab<<<gv, 256, 0, stream>>>(hq, ab);
    k_hbox2<<<BB * HH, 256, 0, stream>>>(ab, hab);
    k_vbox2_tg<<<gv, 256, 0, stream>>>(hab, g, tg, feats);

    dim3 gf(HH / TROWS, BB);                // 32 x 8 = 256 blocks
    k_cnn_fused<<<gf, 512, 0, stream>>>(feats, wf1, wf2, b1, b2, W3, b3, tg, out);
}